// Round 5
// baseline (560.748 us; speedup 1.0000x reference)
//
#include <hip/hip_runtime.h>
#include <hip/hip_bf16.h>
#include <stdint.h>

typedef __attribute__((ext_vector_type(8))) short short8;
typedef __attribute__((ext_vector_type(4))) float f32x4;

static __device__ __forceinline__ ushort f2bf(float f) {
    uint32_t u = __builtin_bit_cast(uint32_t, f);
    uint32_t r = (u + 0x7FFFu + ((u >> 16) & 1u)) >> 16;
    return (ushort)r;
}

static __device__ __forceinline__ void async_copy16(const void* g, void* l) {
    __builtin_amdgcn_global_load_lds(
        (const __attribute__((address_space(1))) uint32_t*)g,
        (__attribute__((address_space(3))) uint32_t*)l, 16, 0, 0);
}

// ---------------- cast fp32 -> bf16 ----------------
__global__ __launch_bounds__(256) void cast_kernel(const float* __restrict__ in,
                                                   ushort* __restrict__ out, int n4) {
    int i = blockIdx.x * 256 + threadIdx.x;
    if (i >= n4) return;
    float4 v = reinterpret_cast<const float4*>(in)[i];
    ushort4 o;
    o.x = f2bf(v.x); o.y = f2bf(v.y); o.z = f2bf(v.z); o.w = f2bf(v.w);
    reinterpret_cast<ushort4*>(out)[i] = o;
}

// ---------------- GEMM: C[M][N] = A[M][K] * B[N][K]^T (bf16 in, fp32 acc) ----------------
// gridDim.x may span multiple concatenated output matrices: which = bx/(N/128).
// B rows addressed globally (weights contiguous); C base advances by which*M*N.
static __device__ __forceinline__ void store_val(float* C, size_t idx, float v) { C[idx] = v; }
static __device__ __forceinline__ void store_val(ushort* C, size_t idx, float v) { C[idx] = f2bf(v); }

template <typename OutT>
__global__ __launch_bounds__(256) void gemm_bt_kernel(const ushort* __restrict__ A,
                                                      const ushort* __restrict__ B,
                                                      OutT* __restrict__ C,
                                                      int M, int N, int K) {
    __shared__ __align__(16) ushort As[128 * 32];
    __shared__ __align__(16) ushort Bs[128 * 32];
    const int tid = threadIdx.x;
    const int w = tid >> 6, lane = tid & 63;
    const int fr = lane & 15, fq = lane >> 4;
    const int wr = w >> 1, wc = w & 1;
    const int bpn = N >> 7;                       // blocks per output matrix
    const int which = blockIdx.x / bpn;
    const int row0 = blockIdx.y * 128;
    const int gcol0 = blockIdx.x * 128;           // global col into concatenated B
    const int col0 = gcol0 - which * N;           // local col within this output
    OutT* Cw = C + (size_t)which * M * N;

    const int srow = tid >> 2;
    const int scol = (tid & 3) * 8;
    const ushort* ga0 = A + (size_t)(row0 + srow) * K + scol;
    const ushort* ga1 = A + (size_t)(row0 + 64 + srow) * K + scol;
    const ushort* gb0 = B + (size_t)(gcol0 + srow) * K + scol;
    const ushort* gb1 = B + (size_t)(gcol0 + 64 + srow) * K + scol;
    ushort* la0 = &As[(w * 64) * 8];
    ushort* la1 = &As[(256 + w * 64) * 8];
    ushort* lb0 = &Bs[(w * 64) * 8];
    ushort* lb1 = &Bs[(256 + w * 64) * 8];

    f32x4 acc[4][4];
#pragma unroll
    for (int m = 0; m < 4; ++m)
#pragma unroll
        for (int n = 0; n < 4; ++n) acc[m][n] = f32x4{0.f, 0.f, 0.f, 0.f};

    for (int kt = 0; kt < K; kt += 32) {
        __syncthreads();
        async_copy16(ga0 + kt, la0);
        async_copy16(ga1 + kt, la1);
        async_copy16(gb0 + kt, lb0);
        async_copy16(gb1 + kt, lb1);
        __syncthreads();
        short8 af[4], bfr[4];
#pragma unroll
        for (int m = 0; m < 4; ++m)
            af[m] = *(const short8*)&As[(wr * 64 + m * 16 + fr) * 32 + fq * 8];
#pragma unroll
        for (int n = 0; n < 4; ++n)
            bfr[n] = *(const short8*)&Bs[(wc * 64 + n * 16 + fr) * 32 + fq * 8];
#pragma unroll
        for (int m = 0; m < 4; ++m)
#pragma unroll
            for (int n = 0; n < 4; ++n)
                acc[m][n] = __builtin_amdgcn_mfma_f32_16x16x32_bf16(af[m], bfr[n], acc[m][n], 0, 0, 0);
    }

#pragma unroll
    for (int m = 0; m < 4; ++m) {
        const int grow = row0 + wr * 64 + m * 16 + fq * 4;
#pragma unroll
        for (int n = 0; n < 4; ++n) {
            const int gcol = col0 + wc * 64 + n * 16 + fr;
#pragma unroll
            for (int r = 0; r < 4; ++r)
                store_val(Cw, (size_t)(grow + r) * N + gcol, acc[m][n][r]);
        }
    }
}

// ---------------- flash attention fwd ----------------
// QBLK=64 (4 waves x 16 q-rows), KBLK=64. LDS exactly 40960 B -> 4 blocks/CU.
__global__ __launch_bounds__(256, 4) void attn_kernel(const ushort* __restrict__ Q,
                                                      const ushort* __restrict__ K,
                                                      const ushort* __restrict__ V,
                                                      ushort* __restrict__ O,
                                                      int S, int HID, float scale) {
    __shared__ __align__(16) ushort Ks[64 * 128];   // swz: byte ^= ((row&7)<<4)
    __shared__ __align__(16) ushort Vt[128 * 64];   // [dh][kv]; swz: byte ^= (((dh&7)^((dh>>4)&7))<<4)
    __shared__ __align__(16) ushort Ps[4][16 * 64]; // packed; swz: byte ^= ((q&7)<<4)

    const int tid = threadIdx.x, w = tid >> 6, lane = tid & 63;
    const int fr = lane & 15, fq = lane >> 4;
    const int qt = blockIdx.x, h = blockIdx.y, b = blockIdx.z;
    const size_t rs = (size_t)HID;
    const int qr0 = qt * 64 + w * 16;

    short8 qf[4];
    {
        const ushort* qp = Q + ((size_t)(b * S) + qr0 + fr) * rs + h * 128 + fq * 8;
#pragma unroll
        for (int ks = 0; ks < 4; ++ks) qf[ks] = *(const short8*)(qp + ks * 32);
    }

    f32x4 of[8];
#pragma unroll
    for (int n = 0; n < 8; ++n) of[n] = f32x4{0.f, 0.f, 0.f, 0.f};
    float m_i[4] = {-1e30f, -1e30f, -1e30f, -1e30f};
    float l_i[4] = {0.f, 0.f, 0.f, 0.f};

    const ushort* Kb = K + (size_t)(b * S) * rs + h * 128;
    const ushort* Vb = V + (size_t)(b * S) * rs + h * 128;

    const int krow = tid >> 4;
    const int kcolb = (tid & 15) << 4;
    const int vpr = tid >> 3;
    const int vc0 = (tid & 7) * 16;
    const int vg  = tid & 7;

    const int nt = S / 64;
    for (int t = 0; t < nt; ++t) {
        __syncthreads();
        // ---- stage K tile (linear LDS dest, swizzled global source) ----
#pragma unroll
        for (int j = 0; j < 4; ++j) {
            int row = j * 16 + krow;
            int lcolb = kcolb ^ ((row & 7) << 4);
            const ushort* src = Kb + (size_t)(t * 64 + row) * rs + (lcolb >> 1);
            async_copy16(src, &Ks[(j * 256 + w * 64) * 8]);
        }
        // ---- stage V transposed (2-way-free swizzled writes) ----
        {
            const int r0 = vpr * 2;
            const ushort* v0 = Vb + (size_t)(t * 64 + r0) * rs + vc0;
            const ushort* v1 = v0 + rs;
            short8 a0 = *(const short8*)(v0);
            short8 a1 = *(const short8*)(v0 + 8);
            short8 b0 = *(const short8*)(v1);
            short8 b1 = *(const short8*)(v1 + 8);
#pragma unroll
            for (int i = 0; i < 16; ++i) {
                int dh = vc0 + i;
                uint32_t lo = (uint32_t)(ushort)(i < 8 ? a0[i] : a1[i - 8]);
                uint32_t hi = (uint32_t)(ushort)(i < 8 ? b0[i] : b1[i - 8]);
                int pb = (dh * 128 + r0 * 2) ^ ((((i & 7) ^ vg) & 7) << 4);
                *(uint32_t*)((char*)Vt + pb) = lo | (hi << 16);
            }
        }
        __syncthreads();

        // ---- S = Q K^T ----
        f32x4 sf[4];
        __builtin_amdgcn_s_setprio(1);
#pragma unroll
        for (int kc = 0; kc < 4; ++kc) {
            f32x4 s = f32x4{0.f, 0.f, 0.f, 0.f};
#pragma unroll
            for (int ks = 0; ks < 4; ++ks) {
                int row = kc * 16 + fr;
                int pb = (row * 256 + ks * 64 + fq * 16) ^ ((row & 7) << 4);
                short8 kf = *(const short8*)((const char*)Ks + pb);
                s = __builtin_amdgcn_mfma_f32_16x16x32_bf16(qf[ks], kf, s, 0, 0, 0);
            }
            sf[kc] = s * scale;
        }
        __builtin_amdgcn_s_setprio(0);

        // ---- online softmax (16-lane-group shuffle reduce) ----
        float mnew[4], sc[4], rsum[4];
#pragma unroll
        for (int r = 0; r < 4; ++r) {
            float tm = fmaxf(fmaxf(sf[0][r], sf[1][r]), fmaxf(sf[2][r], sf[3][r]));
#pragma unroll
            for (int d = 1; d < 16; d <<= 1) tm = fmaxf(tm, __shfl_xor(tm, d));
            mnew[r] = fmaxf(m_i[r], tm);
            sc[r] = __expf(m_i[r] - mnew[r]);
            rsum[r] = 0.f;
        }
#pragma unroll
        for (int kc = 0; kc < 4; ++kc)
#pragma unroll
            for (int r = 0; r < 4; ++r) {
                float p = __expf(sf[kc][r] - mnew[r]);
                sf[kc][r] = p;
                rsum[r] += p;
            }
#pragma unroll
        for (int r = 0; r < 4; ++r) {
#pragma unroll
            for (int d = 1; d < 16; d <<= 1) rsum[r] += __shfl_xor(rsum[r], d);
            l_i[r] = l_i[r] * sc[r] + rsum[r];
            m_i[r] = mnew[r];
        }
#pragma unroll
        for (int n = 0; n < 8; ++n) {
            f32x4 o = of[n];
            o[0] *= sc[0]; o[1] *= sc[1]; o[2] *= sc[2]; o[3] *= sc[3];
            of[n] = o;
        }

        // ---- P -> bf16 -> per-wave LDS (packed, XOR-swizzled) ----
        char* pw = (char*)&Ps[w][0];
#pragma unroll
        for (int kc = 0; kc < 4; ++kc)
#pragma unroll
            for (int r = 0; r < 4; ++r) {
                int q = fq * 4 + r;
                int byte = q * 128 + ((kc * 32 + fr * 2) ^ ((q & 7) << 4));
                *(ushort*)(pw + byte) = f2bf(sf[kc][r]);
            }
        asm volatile("s_waitcnt lgkmcnt(0)" ::: "memory");
        __builtin_amdgcn_sched_barrier(0);

        // ---- O += P V ----
        __builtin_amdgcn_s_setprio(1);
#pragma unroll
        for (int kvc = 0; kvc < 2; ++kvc) {
            int pbyte = fr * 128 + ((kvc * 64 + fq * 16) ^ ((fr & 7) << 4));
            short8 pf = *(const short8*)(pw + pbyte);
#pragma unroll
            for (int n = 0; n < 8; ++n) {
                int row = n * 16 + fr;
                int pb = (row * 128 + kvc * 64 + fq * 16) ^ ((((row & 7) ^ n) & 7) << 4);
                short8 vf = *(const short8*)((const char*)Vt + pb);
                of[n] = __builtin_amdgcn_mfma_f32_16x16x32_bf16(pf, vf, of[n], 0, 0, 0);
            }
        }
        __builtin_amdgcn_s_setprio(0);
    }

    // ---- epilogue ----
    float inv[4];
#pragma unroll
    for (int r = 0; r < 4; ++r) inv[r] = 1.f / l_i[r];
#pragma unroll
    for (int n = 0; n < 8; ++n)
#pragma unroll
        for (int r = 0; r < 4; ++r) {
            size_t idx = ((size_t)(b * S) + qr0 + fq * 4 + r) * rs + h * 128 + n * 16 + fr;
            O[idx] = f2bf(of[n][r] * inv[r]);
        }
}

// ---------------- launch ----------------
extern "C" void kernel_launch(void* const* d_in, const int* in_sizes, int n_in,
                              void* d_out, int out_size, void* d_ws, size_t ws_size,
                              hipStream_t stream) {
    constexpr int B = 2, S = 2048, HID = 2048, H = 16;
    constexpr int M = B * S;
    const float scale = 0.08838834764831845f;

    const float* x  = (const float*)d_in[0];
    const float* wq = (const float*)d_in[1];
    const float* wk = (const float*)d_in[2];
    const float* wv = (const float*)d_in[3];
    const float* wo = (const float*)d_in[4];
    float* out = (float*)d_out;

    char* ws = (char*)d_ws;
    ushort* xb  = (ushort*)(ws);                    // [4096][2048] bf16; reused as attn out
    ushort* wqb = (ushort*)(ws + 16777216);         // wq,wk,wv casts contiguous (24 MB)
    ushort* wkb = (ushort*)(ws + 25165824);
    ushort* wvb = (ushort*)(ws + 33554432);
    ushort* qb  = (ushort*)(ws + 41943040);         // q,k,v contiguous (48 MB)
    ushort* kb  = (ushort*)(ws + 58720256);
    ushort* vb  = (ushort*)(ws + 75497472);

    const int XN = M * HID;
    const int WN = HID * HID;

    cast_kernel<<<XN / 4 / 256, 256, 0, stream>>>(x, xb, XN / 4);
    cast_kernel<<<WN / 4 / 256, 256, 0, stream>>>(wq, wqb, WN / 4);
    cast_kernel<<<WN / 4 / 256, 256, 0, stream>>>(wk, wkb, WN / 4);
    cast_kernel<<<WN / 4 / 256, 256, 0, stream>>>(wv, wvb, WN / 4);

    // fused QKV projection: one GEMM over concatenated weights -> concatenated q,k,v
    dim3 gq(3 * HID / 128, M / 128);   // (48, 32) = 1536 blocks
    gemm_bt_kernel<ushort><<<gq, 256, 0, stream>>>(xb, wqb, qb, M, HID, HID);

    dim3 ga(S / 64, H, B);             // (32, 16, 2) = 1024 blocks
    attn_kernel<<<ga, 256, 0, stream>>>(qb, kb, vb, xb, S, HID, scale);

    cast_kernel<<<WN / 4 / 256, 256, 0, stream>>>(wo, wqb, WN / 4);
    dim3 gg(HID / 128, M / 128);       // (16, 32)
    gemm_bt_kernel<float><<<gg, 256, 0, stream>>>(xb, wqb, out, M, HID, HID);
}

// Round 6
// 396.769 us; speedup vs baseline: 1.4133x; 1.4133x over previous
//
#include <hip/hip_runtime.h>
#include <hip/hip_bf16.h>
#include <stdint.h>

typedef __attribute__((ext_vector_type(8))) short short8;
typedef __attribute__((ext_vector_type(4))) float f32x4;

static __device__ __forceinline__ ushort f2bf(float f) {
    uint32_t u = __builtin_bit_cast(uint32_t, f);
    uint32_t r = (u + 0x7FFFu + ((u >> 16) & 1u)) >> 16;
    return (ushort)r;
}

static __device__ __forceinline__ void async_copy16(const void* g, void* l) {
    __builtin_amdgcn_global_load_lds(
        (const __attribute__((address_space(1))) uint32_t*)g,
        (__attribute__((address_space(3))) uint32_t*)l, 16, 0, 0);
}

// ---------------- cast fp32 -> bf16 ----------------
__global__ __launch_bounds__(256) void cast_kernel(const float* __restrict__ in,
                                                   ushort* __restrict__ out, int n4) {
    int i = blockIdx.x * 256 + threadIdx.x;
    if (i >= n4) return;
    float4 v = reinterpret_cast<const float4*>(in)[i];
    ushort4 o;
    o.x = f2bf(v.x); o.y = f2bf(v.y); o.z = f2bf(v.z); o.w = f2bf(v.w);
    reinterpret_cast<ushort4*>(out)[i] = o;
}

// ---------------- GEMM: C[M][N] = A[M][K] * B[N][K]^T (bf16 in, fp32 acc) ----------------
// gridDim.x may span multiple concatenated output matrices: which = bx/(N/128).
static __device__ __forceinline__ void store_val(float* C, size_t idx, float v) { C[idx] = v; }
static __device__ __forceinline__ void store_val(ushort* C, size_t idx, float v) { C[idx] = f2bf(v); }

template <typename OutT>
__global__ __launch_bounds__(256) void gemm_bt_kernel(const ushort* __restrict__ A,
                                                      const ushort* __restrict__ B,
                                                      OutT* __restrict__ C,
                                                      int M, int N, int K) {
    __shared__ __align__(16) ushort As[128 * 32];
    __shared__ __align__(16) ushort Bs[128 * 32];
    const int tid = threadIdx.x;
    const int w = tid >> 6, lane = tid & 63;
    const int fr = lane & 15, fq = lane >> 4;
    const int wr = w >> 1, wc = w & 1;
    const int bpn = N >> 7;
    const int which = blockIdx.x / bpn;
    const int row0 = blockIdx.y * 128;
    const int gcol0 = blockIdx.x * 128;
    const int col0 = gcol0 - which * N;
    OutT* Cw = C + (size_t)which * M * N;

    const int srow = tid >> 2;
    const int scol = (tid & 3) * 8;
    const ushort* ga0 = A + (size_t)(row0 + srow) * K + scol;
    const ushort* ga1 = A + (size_t)(row0 + 64 + srow) * K + scol;
    const ushort* gb0 = B + (size_t)(gcol0 + srow) * K + scol;
    const ushort* gb1 = B + (size_t)(gcol0 + 64 + srow) * K + scol;
    ushort* la0 = &As[(w * 64) * 8];
    ushort* la1 = &As[(256 + w * 64) * 8];
    ushort* lb0 = &Bs[(w * 64) * 8];
    ushort* lb1 = &Bs[(256 + w * 64) * 8];

    f32x4 acc[4][4];
#pragma unroll
    for (int m = 0; m < 4; ++m)
#pragma unroll
        for (int n = 0; n < 4; ++n) acc[m][n] = f32x4{0.f, 0.f, 0.f, 0.f};

    for (int kt = 0; kt < K; kt += 32) {
        __syncthreads();
        async_copy16(ga0 + kt, la0);
        async_copy16(ga1 + kt, la1);
        async_copy16(gb0 + kt, lb0);
        async_copy16(gb1 + kt, lb1);
        __syncthreads();
        short8 af[4], bfr[4];
#pragma unroll
        for (int m = 0; m < 4; ++m)
            af[m] = *(const short8*)&As[(wr * 64 + m * 16 + fr) * 32 + fq * 8];
#pragma unroll
        for (int n = 0; n < 4; ++n)
            bfr[n] = *(const short8*)&Bs[(wc * 64 + n * 16 + fr) * 32 + fq * 8];
#pragma unroll
        for (int m = 0; m < 4; ++m)
#pragma unroll
            for (int n = 0; n < 4; ++n)
                acc[m][n] = __builtin_amdgcn_mfma_f32_16x16x32_bf16(af[m], bfr[n], acc[m][n], 0, 0, 0);
    }

#pragma unroll
    for (int m = 0; m < 4; ++m) {
        const int grow = row0 + wr * 64 + m * 16 + fq * 4;
#pragma unroll
        for (int n = 0; n < 4; ++n) {
            const int gcol = col0 + wc * 64 + n * 16 + fr;
#pragma unroll
            for (int r = 0; r < 4; ++r)
                store_val(Cw, (size_t)(grow + r) * N + gcol, acc[m][n][r]);
        }
    }
}

// ---------------- flash attention fwd ----------------
// QBLK=64 (4 waves x 16 q-rows), KBLK=64. LDS exactly 40960 B.
// Plain launch_bounds: R5 showed (256,4) forces VGPR=64 -> compiler re-reads Q
// from global every tile (+473 MB HBM). Let VGPR land ~96-112.
__global__ __launch_bounds__(256) void attn_kernel(const ushort* __restrict__ Q,
                                                   const ushort* __restrict__ K,
                                                   const ushort* __restrict__ V,
                                                   ushort* __restrict__ O,
                                                   int S, int HID, float scale) {
    __shared__ __align__(16) ushort Ks[64 * 128];   // swz: byte ^= ((row&7)<<4)
    __shared__ __align__(16) ushort Vt[128 * 64];   // [dh][kv]; swz: byte ^= (((dh&7)^((dh>>4)&7))<<4)
    __shared__ __align__(16) ushort Ps[4][16 * 64]; // packed; swz: byte ^= ((q&7)<<4)

    const int tid = threadIdx.x, w = tid >> 6, lane = tid & 63;
    const int fr = lane & 15, fq = lane >> 4;
    const int qt = blockIdx.x, h = blockIdx.y, b = blockIdx.z;
    const size_t rs = (size_t)HID;
    const int qr0 = qt * 64 + w * 16;

    short8 qf[4];
    {
        const ushort* qp = Q + ((size_t)(b * S) + qr0 + fr) * rs + h * 128 + fq * 8;
#pragma unroll
        for (int ks = 0; ks < 4; ++ks) qf[ks] = *(const short8*)(qp + ks * 32);
    }

    f32x4 of[8];
#pragma unroll
    for (int n = 0; n < 8; ++n) of[n] = f32x4{0.f, 0.f, 0.f, 0.f};
    float m_i[4] = {-1e30f, -1e30f, -1e30f, -1e30f};
    float l_i[4] = {0.f, 0.f, 0.f, 0.f};

    const ushort* Kb = K + (size_t)(b * S) * rs + h * 128;
    const ushort* Vb = V + (size_t)(b * S) * rs + h * 128;

    const int krow = tid >> 4;
    const int kcolb = (tid & 15) << 4;
    const int vpr = tid >> 3;
    const int vc0 = (tid & 7) * 16;
    const int vg  = tid & 7;

    const int nt = S / 64;
    for (int t = 0; t < nt; ++t) {
        __syncthreads();
        // ---- stage K tile (linear LDS dest, swizzled global source) ----
#pragma unroll
        for (int j = 0; j < 4; ++j) {
            int row = j * 16 + krow;
            int lcolb = kcolb ^ ((row & 7) << 4);
            const ushort* src = Kb + (size_t)(t * 64 + row) * rs + (lcolb >> 1);
            async_copy16(src, &Ks[(j * 256 + w * 64) * 8]);
        }
        // ---- stage V transposed (2-way-free swizzled writes) ----
        {
            const int r0 = vpr * 2;
            const ushort* v0 = Vb + (size_t)(t * 64 + r0) * rs + vc0;
            const ushort* v1 = v0 + rs;
            short8 a0 = *(const short8*)(v0);
            short8 a1 = *(const short8*)(v0 + 8);
            short8 b0 = *(const short8*)(v1);
            short8 b1 = *(const short8*)(v1 + 8);
#pragma unroll
            for (int i = 0; i < 16; ++i) {
                int dh = vc0 + i;
                uint32_t lo = (uint32_t)(ushort)(i < 8 ? a0[i] : a1[i - 8]);
                uint32_t hi = (uint32_t)(ushort)(i < 8 ? b0[i] : b1[i - 8]);
                int pb = (dh * 128 + r0 * 2) ^ ((((i & 7) ^ vg) & 7) << 4);
                *(uint32_t*)((char*)Vt + pb) = lo | (hi << 16);
            }
        }
        __syncthreads();

        // ---- S = Q K^T ----
        f32x4 sf[4];
        __builtin_amdgcn_s_setprio(1);
#pragma unroll
        for (int kc = 0; kc < 4; ++kc) {
            f32x4 s = f32x4{0.f, 0.f, 0.f, 0.f};
#pragma unroll
            for (int ks = 0; ks < 4; ++ks) {
                int row = kc * 16 + fr;
                int pb = (row * 256 + ks * 64 + fq * 16) ^ ((row & 7) << 4);
                short8 kf = *(const short8*)((const char*)Ks + pb);
                s = __builtin_amdgcn_mfma_f32_16x16x32_bf16(qf[ks], kf, s, 0, 0, 0);
            }
            sf[kc] = s * scale;
        }
        __builtin_amdgcn_s_setprio(0);

        // ---- online softmax (16-lane-group shuffle reduce) ----
        float mnew[4], sc[4], rsum[4];
#pragma unroll
        for (int r = 0; r < 4; ++r) {
            float tm = fmaxf(fmaxf(sf[0][r], sf[1][r]), fmaxf(sf[2][r], sf[3][r]));
#pragma unroll
            for (int d = 1; d < 16; d <<= 1) tm = fmaxf(tm, __shfl_xor(tm, d));
            mnew[r] = fmaxf(m_i[r], tm);
            sc[r] = __expf(m_i[r] - mnew[r]);
            rsum[r] = 0.f;
        }
#pragma unroll
        for (int kc = 0; kc < 4; ++kc)
#pragma unroll
            for (int r = 0; r < 4; ++r) {
                float p = __expf(sf[kc][r] - mnew[r]);
                sf[kc][r] = p;
                rsum[r] += p;
            }
#pragma unroll
        for (int r = 0; r < 4; ++r) {
#pragma unroll
            for (int d = 1; d < 16; d <<= 1) rsum[r] += __shfl_xor(rsum[r], d);
            l_i[r] = l_i[r] * sc[r] + rsum[r];
            m_i[r] = mnew[r];
        }
#pragma unroll
        for (int n = 0; n < 8; ++n) {
            f32x4 o = of[n];
            o[0] *= sc[0]; o[1] *= sc[1]; o[2] *= sc[2]; o[3] *= sc[3];
            of[n] = o;
        }

        // ---- P -> bf16 -> per-wave LDS (packed, XOR-swizzled) ----
        char* pw = (char*)&Ps[w][0];
#pragma unroll
        for (int kc = 0; kc < 4; ++kc)
#pragma unroll
            for (int r = 0; r < 4; ++r) {
                int q = fq * 4 + r;
                int byte = q * 128 + ((kc * 32 + fr * 2) ^ ((q & 7) << 4));
                *(ushort*)(pw + byte) = f2bf(sf[kc][r]);
            }
        asm volatile("s_waitcnt lgkmcnt(0)" ::: "memory");
        __builtin_amdgcn_sched_barrier(0);

        // ---- O += P V ----
        __builtin_amdgcn_s_setprio(1);
#pragma unroll
        for (int kvc = 0; kvc < 2; ++kvc) {
            int pbyte = fr * 128 + ((kvc * 64 + fq * 16) ^ ((fr & 7) << 4));
            short8 pf = *(const short8*)(pw + pbyte);
#pragma unroll
            for (int n = 0; n < 8; ++n) {
                int row = n * 16 + fr;
                int pb = (row * 128 + kvc * 64 + fq * 16) ^ ((((row & 7) ^ n) & 7) << 4);
                short8 vf = *(const short8*)((const char*)Vt + pb);
                of[n] = __builtin_amdgcn_mfma_f32_16x16x32_bf16(pf, vf, of[n], 0, 0, 0);
            }
        }
        __builtin_amdgcn_s_setprio(0);
    }

    // ---- epilogue ----
    float inv[4];
#pragma unroll
    for (int r = 0; r < 4; ++r) inv[r] = 1.f / l_i[r];
#pragma unroll
    for (int n = 0; n < 8; ++n)
#pragma unroll
        for (int r = 0; r < 4; ++r) {
            size_t idx = ((size_t)(b * S) + qr0 + fq * 4 + r) * rs + h * 128 + n * 16 + fr;
            O[idx] = f2bf(of[n][r] * inv[r]);
        }
}

// ---------------- launch ----------------
extern "C" void kernel_launch(void* const* d_in, const int* in_sizes, int n_in,
                              void* d_out, int out_size, void* d_ws, size_t ws_size,
                              hipStream_t stream) {
    constexpr int B = 2, S = 2048, HID = 2048, H = 16;
    constexpr int M = B * S;
    const float scale = 0.08838834764831845f;

    const float* x  = (const float*)d_in[0];
    const float* wq = (const float*)d_in[1];
    const float* wk = (const float*)d_in[2];
    const float* wv = (const float*)d_in[3];
    const float* wo = (const float*)d_in[4];
    float* out = (float*)d_out;

    char* ws = (char*)d_ws;
    ushort* xb  = (ushort*)(ws);                    // [4096][2048] bf16; reused as attn out
    ushort* wqb = (ushort*)(ws + 16777216);         // wq,wk,wv casts contiguous (24 MB)
    ushort* wkb = (ushort*)(ws + 25165824);
    ushort* wvb = (ushort*)(ws + 33554432);
    ushort* qb  = (ushort*)(ws + 41943040);         // q,k,v contiguous (48 MB)
    ushort* kb  = (ushort*)(ws + 58720256);
    ushort* vb  = (ushort*)(ws + 75497472);

    const int XN = M * HID;
    const int WN = HID * HID;

    cast_kernel<<<XN / 4 / 256, 256, 0, stream>>>(x, xb, XN / 4);
    cast_kernel<<<WN / 4 / 256, 256, 0, stream>>>(wq, wqb, WN / 4);
    cast_kernel<<<WN / 4 / 256, 256, 0, stream>>>(wk, wkb, WN / 4);
    cast_kernel<<<WN / 4 / 256, 256, 0, stream>>>(wv, wvb, WN / 4);

    // fused QKV projection: one GEMM over concatenated weights -> concatenated q,k,v
    dim3 gq(3 * HID / 128, M / 128);   // (48, 32) = 1536 blocks
    gemm_bt_kernel<ushort><<<gq, 256, 0, stream>>>(xb, wqb, qb, M, HID, HID);

    dim3 ga(S / 64, H, B);             // (32, 16, 2) = 1024 blocks
    attn_kernel<<<ga, 256, 0, stream>>>(qb, kb, vb, xb, S, HID, scale);

    cast_kernel<<<WN / 4 / 256, 256, 0, stream>>>(wo, wqb, WN / 4);
    dim3 gg(HID / 128, M / 128);       // (16, 32)
    gemm_bt_kernel<float><<<gg, 256, 0, stream>>>(xb, wqb, out, M, HID, HID);
}

// Round 8
// 389.589 us; speedup vs baseline: 1.4393x; 1.0184x over previous
//
#include <hip/hip_runtime.h>
#include <hip/hip_bf16.h>
#include <stdint.h>

typedef __attribute__((ext_vector_type(8))) short short8;
typedef __attribute__((ext_vector_type(4))) short short4v;
typedef __attribute__((ext_vector_type(4))) float f32x4;

static __device__ __forceinline__ ushort f2bf(float f) {
    uint32_t u = __builtin_bit_cast(uint32_t, f);
    uint32_t r = (u + 0x7FFFu + ((u >> 16) & 1u)) >> 16;
    return (ushort)r;
}

static __device__ __forceinline__ void async_copy16(const void* g, void* l) {
    __builtin_amdgcn_global_load_lds(
        (const __attribute__((address_space(1))) uint32_t*)g,
        (__attribute__((address_space(3))) uint32_t*)l, 16, 0, 0);
}

// ds_read_b64_tr_b16 semantics (model fitting m156+m162+m222):
//   tile = addr & ~127 (128B subtile = [4][16] bf16 row-major)
//   col  = (addr >> 3) & 15      <-- column selected by addr bits [6:3]
//   returns 4 bf16 at tile + col*2 + {0,32,64,96}
static __device__ __forceinline__ short4v tr16(const ushort* p) {
    short4v d;
    const __attribute__((address_space(3))) ushort* p3 =
        (const __attribute__((address_space(3))) ushort*)p;
    asm volatile("ds_read_b64_tr_b16 %0, %1" : "=v"(d) : "v"(p3));
    return d;
}

// ---------------- cast fp32 -> bf16 ----------------
__global__ __launch_bounds__(256) void cast_kernel(const float* __restrict__ in,
                                                   ushort* __restrict__ out, int n4) {
    int i = blockIdx.x * 256 + threadIdx.x;
    if (i >= n4) return;
    float4 v = reinterpret_cast<const float4*>(in)[i];
    ushort4 o;
    o.x = f2bf(v.x); o.y = f2bf(v.y); o.z = f2bf(v.z); o.w = f2bf(v.w);
    reinterpret_cast<ushort4*>(out)[i] = o;
}

// ---------------- GEMM: C[M][N] = A[M][K] * B[N][K]^T (bf16 in, fp32 acc) ----------------
static __device__ __forceinline__ void store_val(float* C, size_t idx, float v) { C[idx] = v; }
static __device__ __forceinline__ void store_val(ushort* C, size_t idx, float v) { C[idx] = f2bf(v); }

template <typename OutT>
__global__ __launch_bounds__(256) void gemm_bt_kernel(const ushort* __restrict__ A,
                                                      const ushort* __restrict__ B,
                                                      OutT* __restrict__ C,
                                                      int M, int N, int K) {
    __shared__ __align__(16) ushort As[128 * 32];
    __shared__ __align__(16) ushort Bs[128 * 32];
    const int tid = threadIdx.x;
    const int w = tid >> 6, lane = tid & 63;
    const int fr = lane & 15, fq = lane >> 4;
    const int wr = w >> 1, wc = w & 1;
    const int bpn = N >> 7;
    const int which = blockIdx.x / bpn;
    const int row0 = blockIdx.y * 128;
    const int gcol0 = blockIdx.x * 128;
    const int col0 = gcol0 - which * N;
    OutT* Cw = C + (size_t)which * M * N;

    const int srow = tid >> 2;
    const int scol = (tid & 3) * 8;
    const ushort* ga0 = A + (size_t)(row0 + srow) * K + scol;
    const ushort* ga1 = A + (size_t)(row0 + 64 + srow) * K + scol;
    const ushort* gb0 = B + (size_t)(gcol0 + srow) * K + scol;
    const ushort* gb1 = B + (size_t)(gcol0 + 64 + srow) * K + scol;
    ushort* la0 = &As[(w * 64) * 8];
    ushort* la1 = &As[(256 + w * 64) * 8];
    ushort* lb0 = &Bs[(w * 64) * 8];
    ushort* lb1 = &Bs[(256 + w * 64) * 8];

    f32x4 acc[4][4];
#pragma unroll
    for (int m = 0; m < 4; ++m)
#pragma unroll
        for (int n = 0; n < 4; ++n) acc[m][n] = f32x4{0.f, 0.f, 0.f, 0.f};

    for (int kt = 0; kt < K; kt += 32) {
        __syncthreads();
        async_copy16(ga0 + kt, la0);
        async_copy16(ga1 + kt, la1);
        async_copy16(gb0 + kt, lb0);
        async_copy16(gb1 + kt, lb1);
        __syncthreads();
        short8 af[4], bfr[4];
#pragma unroll
        for (int m = 0; m < 4; ++m)
            af[m] = *(const short8*)&As[(wr * 64 + m * 16 + fr) * 32 + fq * 8];
#pragma unroll
        for (int n = 0; n < 4; ++n)
            bfr[n] = *(const short8*)&Bs[(wc * 64 + n * 16 + fr) * 32 + fq * 8];
#pragma unroll
        for (int m = 0; m < 4; ++m)
#pragma unroll
            for (int n = 0; n < 4; ++n)
                acc[m][n] = __builtin_amdgcn_mfma_f32_16x16x32_bf16(af[m], bfr[n], acc[m][n], 0, 0, 0);
    }

#pragma unroll
    for (int m = 0; m < 4; ++m) {
        const int grow = row0 + wr * 64 + m * 16 + fq * 4;
#pragma unroll
        for (int n = 0; n < 4; ++n) {
            const int gcol = col0 + wc * 64 + n * 16 + fr;
#pragma unroll
            for (int r = 0; r < 4; ++r)
                store_val(Cw, (size_t)(grow + r) * N + gcol, acc[m][n][r]);
        }
    }
}

// ---------------- flash attention fwd ----------------
// QBLK=64 (4 waves x 16 q-rows), KBLK=64. LDS exactly 40960 B.
// V staged via global_load_lds into [kv/4][dh/16][4][16] subtiled layout;
// element (kv,dh) at byte L*128 + (kv&3)*32 + (dh&15)*2, L=(kv>>2)*8+(dh>>4).
// PV B-fragments via ds_read_b64_tr_b16 at addr L*128 + col*8.
__global__ __launch_bounds__(256) void attn_kernel(const ushort* __restrict__ Q,
                                                   const ushort* __restrict__ K,
                                                   const ushort* __restrict__ V,
                                                   ushort* __restrict__ O,
                                                   int S, int HID, float scale) {
    __shared__ __align__(16) ushort Ks[64 * 128];   // swz: byte ^= ((row&7)<<4)
    __shared__ __align__(16) ushort Vs[64 * 128];   // subtiled (see above)
    __shared__ __align__(16) ushort Ps[4][16 * 64]; // packed; swz: byte ^= ((q&7)<<4)

    const int tid = threadIdx.x, w = tid >> 6, lane = tid & 63;
    const int fr = lane & 15, fq = lane >> 4;
    const int qt = blockIdx.x, h = blockIdx.y, b = blockIdx.z;
    const size_t rs = (size_t)HID;
    const int qr0 = qt * 64 + w * 16;

    short8 qf[4];
    {
        const ushort* qp = Q + ((size_t)(b * S) + qr0 + fr) * rs + h * 128 + fq * 8;
#pragma unroll
        for (int ks = 0; ks < 4; ++ks) qf[ks] = *(const short8*)(qp + ks * 32);
    }

    f32x4 of[8];
#pragma unroll
    for (int n = 0; n < 8; ++n) of[n] = f32x4{0.f, 0.f, 0.f, 0.f};
    float m_i[4] = {-1e30f, -1e30f, -1e30f, -1e30f};
    float l_i[4] = {0.f, 0.f, 0.f, 0.f};

    const ushort* Kb = K + (size_t)(b * S) * rs + h * 128;
    const ushort* Vb = V + (size_t)(b * S) * rs + h * 128;

    const int krow = tid >> 4;
    const int kcolb = (tid & 15) << 4;

    // V staging source offsets (per gload instr p): LDS byte A=p*4096+w*1024+lane*16
    // -> L=p*32+w*8+(lane>>3), kv=(L>>3)*4+((lane>>1)&3), dh=(L&7)*16+(lane&1)*8
    size_t voff[4];
#pragma unroll
    for (int p = 0; p < 4; ++p) {
        int L = p * 32 + w * 8 + (lane >> 3);
        int kv = (L >> 3) * 4 + ((lane >> 1) & 3);
        int dh = (L & 7) * 16 + (lane & 1) * 8;
        voff[p] = (size_t)kv * rs + dh;
    }

    const int nt = S / 64;
    for (int t = 0; t < nt; ++t) {
        __syncthreads();
        // ---- stage K tile (linear LDS dest, swizzled global source) ----
#pragma unroll
        for (int j = 0; j < 4; ++j) {
            int row = j * 16 + krow;
            int lcolb = kcolb ^ ((row & 7) << 4);
            const ushort* src = Kb + (size_t)(t * 64 + row) * rs + (lcolb >> 1);
            async_copy16(src, &Ks[(j * 256 + w * 64) * 8]);
        }
        // ---- stage V subtiled via global_load_lds (zero VALU transpose) ----
        {
            const ushort* vsrc = Vb + (size_t)t * 64 * rs;
#pragma unroll
            for (int p = 0; p < 4; ++p)
                async_copy16(vsrc + voff[p], &Vs[p * 2048 + w * 512]);
        }
        __syncthreads();

        // ---- S = Q K^T ----
        f32x4 sf[4];
        __builtin_amdgcn_s_setprio(1);
#pragma unroll
        for (int kc = 0; kc < 4; ++kc) {
            f32x4 s = f32x4{0.f, 0.f, 0.f, 0.f};
#pragma unroll
            for (int ks = 0; ks < 4; ++ks) {
                int row = kc * 16 + fr;
                int pb = (row * 256 + ks * 64 + fq * 16) ^ ((row & 7) << 4);
                short8 kf = *(const short8*)((const char*)Ks + pb);
                s = __builtin_amdgcn_mfma_f32_16x16x32_bf16(qf[ks], kf, s, 0, 0, 0);
            }
            sf[kc] = s * scale;
        }
        __builtin_amdgcn_s_setprio(0);

        // ---- online softmax (16-lane-group shuffle reduce) ----
        float mnew[4], sc[4], rsum[4];
#pragma unroll
        for (int r = 0; r < 4; ++r) {
            float tm = fmaxf(fmaxf(sf[0][r], sf[1][r]), fmaxf(sf[2][r], sf[3][r]));
#pragma unroll
            for (int d = 1; d < 16; d <<= 1) tm = fmaxf(tm, __shfl_xor(tm, d));
            mnew[r] = fmaxf(m_i[r], tm);
            sc[r] = __expf(m_i[r] - mnew[r]);
            rsum[r] = 0.f;
        }
#pragma unroll
        for (int kc = 0; kc < 4; ++kc)
#pragma unroll
            for (int r = 0; r < 4; ++r) {
                float p = __expf(sf[kc][r] - mnew[r]);
                sf[kc][r] = p;
                rsum[r] += p;
            }
#pragma unroll
        for (int r = 0; r < 4; ++r) {
#pragma unroll
            for (int d = 1; d < 16; d <<= 1) rsum[r] += __shfl_xor(rsum[r], d);
            l_i[r] = l_i[r] * sc[r] + rsum[r];
            m_i[r] = mnew[r];
        }
#pragma unroll
        for (int n = 0; n < 8; ++n) {
            f32x4 o = of[n];
            o[0] *= sc[0]; o[1] *= sc[1]; o[2] *= sc[2]; o[3] *= sc[3];
            of[n] = o;
        }

        // ---- P -> bf16 -> per-wave LDS (packed, XOR-swizzled) ----
        char* pw = (char*)&Ps[w][0];
#pragma unroll
        for (int kc = 0; kc < 4; ++kc)
#pragma unroll
            for (int r = 0; r < 4; ++r) {
                int q = fq * 4 + r;
                int byte = q * 128 + ((kc * 32 + fr * 2) ^ ((q & 7) << 4));
                *(ushort*)(pw + byte) = f2bf(sf[kc][r]);
            }
        asm volatile("s_waitcnt lgkmcnt(0)" ::: "memory");
        __builtin_amdgcn_sched_barrier(0);

        // ---- O += P V  (B-fragments via hardware transpose reads) ----
        __builtin_amdgcn_s_setprio(1);
#pragma unroll
        for (int kvc = 0; kvc < 2; ++kvc) {
            int pbyte = fr * 128 + ((kvc * 64 + fq * 16) ^ ((fr & 7) << 4));
            short8 pf = *(const short8*)(pw + pbyte);
#pragma unroll
            for (int nb = 0; nb < 2; ++nb) {
                short4v vr[4][2];
#pragma unroll
                for (int nn = 0; nn < 4; ++nn)
#pragma unroll
                    for (int hf = 0; hf < 2; ++hf) {
                        int n = nb * 4 + nn;
                        int L = (kvc * 8 + fq * 2 + hf) * 8 + n;
                        // column fr selected by addr bits[6:3] -> fr*8
                        vr[nn][hf] = tr16((const ushort*)((const char*)Vs + L * 128 + fr * 8));
                    }
                asm volatile("s_waitcnt lgkmcnt(0)" ::: "memory");
                __builtin_amdgcn_sched_barrier(0);
#pragma unroll
                for (int nn = 0; nn < 4; ++nn) {
                    int n = nb * 4 + nn;
                    short8 vf = __builtin_shufflevector(vr[nn][0], vr[nn][1], 0, 1, 2, 3, 4, 5, 6, 7);
                    of[n] = __builtin_amdgcn_mfma_f32_16x16x32_bf16(pf, vf, of[n], 0, 0, 0);
                }
            }
        }
        __builtin_amdgcn_s_setprio(0);
    }

    // ---- epilogue ----
    float inv[4];
#pragma unroll
    for (int r = 0; r < 4; ++r) inv[r] = 1.f / l_i[r];
#pragma unroll
    for (int n = 0; n < 8; ++n)
#pragma unroll
        for (int r = 0; r < 4; ++r) {
            size_t idx = ((size_t)(b * S) + qr0 + fq * 4 + r) * rs + h * 128 + n * 16 + fr;
            O[idx] = f2bf(of[n][r] * inv[r]);
        }
}

// ---------------- launch ----------------
extern "C" void kernel_launch(void* const* d_in, const int* in_sizes, int n_in,
                              void* d_out, int out_size, void* d_ws, size_t ws_size,
                              hipStream_t stream) {
    constexpr int B = 2, S = 2048, HID = 2048, H = 16;
    constexpr int M = B * S;
    const float scale = 0.08838834764831845f;

    const float* x  = (const float*)d_in[0];
    const float* wq = (const float*)d_in[1];
    const float* wk = (const float*)d_in[2];
    const float* wv = (const float*)d_in[3];
    const float* wo = (const float*)d_in[4];
    float* out = (float*)d_out;

    char* ws = (char*)d_ws;
    ushort* xb  = (ushort*)(ws);                    // [4096][2048] bf16; reused as attn out
    ushort* wqb = (ushort*)(ws + 16777216);         // wq,wk,wv casts contiguous (24 MB)
    ushort* wkb = (ushort*)(ws + 25165824);
    ushort* wvb = (ushort*)(ws + 33554432);
    ushort* qb  = (ushort*)(ws + 41943040);         // q,k,v contiguous (48 MB)
    ushort* kb  = (ushort*)(ws + 58720256);
    ushort* vb  = (ushort*)(ws + 75497472);

    const int XN = M * HID;
    const int WN = HID * HID;

    cast_kernel<<<XN / 4 / 256, 256, 0, stream>>>(x, xb, XN / 4);
    cast_kernel<<<WN / 4 / 256, 256, 0, stream>>>(wq, wqb, WN / 4);
    cast_kernel<<<WN / 4 / 256, 256, 0, stream>>>(wk, wkb, WN / 4);
    cast_kernel<<<WN / 4 / 256, 256, 0, stream>>>(wv, wvb, WN / 4);

    // fused QKV projection: one GEMM over concatenated weights -> concatenated q,k,v
    dim3 gq(3 * HID / 128, M / 128);   // (48, 32) = 1536 blocks
    gemm_bt_kernel<ushort><<<gq, 256, 0, stream>>>(xb, wqb, qb, M, HID, HID);

    dim3 ga(S / 64, H, B);             // (32, 16, 2) = 1024 blocks
    attn_kernel<<<ga, 256, 0, stream>>>(qb, kb, vb, xb, S, HID, scale);

    cast_kernel<<<WN / 4 / 256, 256, 0, stream>>>(wo, wqb, WN / 4);
    dim3 gg(HID / 128, M / 128);       // (16, 32)
    gemm_bt_kernel<float><<<gg, 256, 0, stream>>>(xb, wqb, out, M, HID, HID);
}